// Round 1
// baseline (476.361 us; speedup 1.0000x reference)
//
#include <hip/hip_runtime.h>

#define NNODES 10000
#define NEDGES 160000
#define MPAD   10112      // 79 * 128
#define FIN    768
#define D2     1024
#define TSTEPS 50

typedef __bf16 bf16x8 __attribute__((ext_vector_type(8)));
typedef float  f32x4  __attribute__((ext_vector_type(4)));

__device__ __forceinline__ unsigned short f2bf(float f) {
    unsigned u = __builtin_bit_cast(unsigned, f);
    u += 0x7FFFu + ((u >> 16) & 1u);
    return (unsigned short)(u >> 16);
}
__device__ __forceinline__ void unpk(unsigned u, float& a, float& b) {
    a = __builtin_bit_cast(float, u << 16);
    b = __builtin_bit_cast(float, u & 0xFFFF0000u);
}

// ---------------- schedule (cosine) ----------------
__global__ void sched_init(float* sched) {
    if (threadIdx.x == 0 && blockIdx.x == 0) {
        const double PI = 3.14159265358979323846;
        double acp = 1.0;
        for (int i = 0; i < TSTEPS; ++i) {
            double x0 = (double)i / (double)TSTEPS;
            double x1 = (double)(i + 1) / (double)TSTEPS;
            double c0 = cos((x0 + 0.008) / 1.008 * PI * 0.5);
            double c1 = cos((x1 + 0.008) / 1.008 * PI * 0.5);
            double a0 = c0 * c0, a1 = c1 * c1;
            double beta = 1.0 - a1 / a0;
            if (beta < 0.0) beta = 0.0;
            if (beta > 0.999) beta = 0.999;
            acp *= (1.0 - beta);
            sched[i]      = (float)sqrt(acp);
            sched[64 + i] = (float)sqrt(1.0 - acp);
        }
    }
}

// ---------------- CSR build ----------------
__global__ void csr_init(int* cnt) {
    int g = blockIdx.x * 256 + threadIdx.x;
    if (g < NNODES) cnt[g] = 1;   // self loop
}
__global__ void csr_count(const int* __restrict__ ei, int* cnt) {
    int g = blockIdx.x * 256 + threadIdx.x;
    if (g < NEDGES) atomicAdd(&cnt[ei[NEDGES + g]], 1);
}
__global__ void csr_scan(const int* __restrict__ cnt, int* rowp, int* cur) {
    __shared__ int part[1024];
    int tid = threadIdx.x;
    const int per = 10;
    int base = tid * per;
    int local[per];
    int s = 0;
    #pragma unroll
    for (int i = 0; i < per; ++i) {
        int idx = base + i;
        int v = (idx < NNODES) ? cnt[idx] : 0;
        local[i] = s;
        s += v;
    }
    part[tid] = s;
    __syncthreads();
    for (int off = 1; off < 1024; off <<= 1) {
        int v = (tid >= off) ? part[tid - off] : 0;
        __syncthreads();
        part[tid] += v;
        __syncthreads();
    }
    int offset = (tid > 0) ? part[tid - 1] : 0;
    #pragma unroll
    for (int i = 0; i < per; ++i) {
        int idx = base + i;
        if (idx < NNODES) {
            int v = offset + local[i];
            rowp[idx] = v;
            cur[idx]  = v;
        } else if (idx == NNODES) {
            rowp[NNODES] = offset + local[i];
        }
    }
}
__global__ void csr_fill(const int* __restrict__ ei, int* cur, int* colv) {
    int g = blockIdx.x * 256 + threadIdx.x;
    if (g < NEDGES) {
        int s = ei[g];
        int d = ei[NEDGES + g];
        int pos = atomicAdd(&cur[d], 1);
        colv[pos] = s;
    } else if (g < NEDGES + NNODES) {
        int d = g - NEDGES;
        int pos = atomicAdd(&cur[d], 1);
        colv[pos] = d;
    }
}

// ---------------- weight prep: fp32 [K][Nn] -> bf16 [Nn][K] ----------------
__global__ void prep_w(const float* __restrict__ W, unsigned short* __restrict__ Wt,
                       int K, int Nn) {
    int g = blockIdx.x * 256 + threadIdx.x;
    if (g >= K * Nn) return;
    int n = g / K, k = g % K;
    Wt[g] = f2bf(W[(size_t)k * Nn + n]);
}

// ---------------- diffusion noise add -> bf16 ----------------
__global__ void x0_kernel(const float* __restrict__ emb, const float* __restrict__ noise,
                          const int* __restrict__ t, const float* __restrict__ sched,
                          unsigned short* __restrict__ x0b) {
    int i4 = blockIdx.x * 256 + threadIdx.x;
    if (i4 >= MPAD * (FIN / 4)) return;
    int row = i4 / (FIN / 4);
    int c = (i4 % (FIN / 4)) * 4;
    unsigned short* dst = x0b + (size_t)row * FIN + c;
    if (row < NNODES) {
        int tv = t[row];
        float sa = sched[tv], so = sched[64 + tv];
        float4 e = *(const float4*)(emb + (size_t)row * FIN + c);
        float4 nz = *(const float4*)(noise + (size_t)row * FIN + c);
        float v0 = sa * e.x + so * nz.x;
        float v1 = sa * e.y + so * nz.y;
        float v2 = sa * e.z + so * nz.z;
        float v3 = sa * e.w + so * nz.w;
        uint2 pk;
        pk.x = (unsigned)f2bf(v0) | ((unsigned)f2bf(v1) << 16);
        pk.y = (unsigned)f2bf(v2) | ((unsigned)f2bf(v3) << 16);
        *(uint2*)dst = pk;
    } else {
        uint2 pk; pk.x = 0u; pk.y = 0u;
        *(uint2*)dst = pk;
    }
}

// ---------------- bf16 MFMA GEMM: C[M][Nn] = A[M][K] @ Bt[Nn][K]^T + bias ----------------
template<bool OUT_BF16>
__global__ void __launch_bounds__(256)
gemm_k(const unsigned short* __restrict__ A, const unsigned short* __restrict__ Bt,
       const float* __restrict__ bias, void* __restrict__ C,
       int K, int Nn, int Mstore) {
    __shared__ __align__(16) unsigned short As[128 * 64];
    __shared__ __align__(16) unsigned short Bs[128 * 64];

    const int tid = threadIdx.x;
    const int lane = tid & 63;
    const int wv = tid >> 6;
    const int wm = wv >> 1, wn = wv & 1;
    const int lr = lane & 15;
    const int kq = lane >> 4;

    const int rowBase = blockIdx.x * 128;
    const int colBase = blockIdx.y * 128;

    f32x4 acc[4][4];
    #pragma unroll
    for (int m = 0; m < 4; ++m)
        #pragma unroll
        for (int n = 0; n < 4; ++n)
            acc[m][n] = (f32x4){0.f, 0.f, 0.f, 0.f};

    const int stageRow = tid >> 3;            // 0..31
    const int stageC8 = (tid & 7) * 8;        // elem offset

    const unsigned short* aBase = A + (size_t)(rowBase + stageRow) * K + stageC8;
    const unsigned short* bBase = Bt + (size_t)(colBase + stageRow) * K + stageC8;
    unsigned short* asDst = &As[stageRow * 64 + stageC8];
    unsigned short* bsDst = &Bs[stageRow * 64 + stageC8];

    for (int kt = 0; kt < K; kt += 64) {
        uint4 av[4], bv[4];
        #pragma unroll
        for (int r = 0; r < 4; ++r) {
            av[r] = *(const uint4*)(aBase + (size_t)r * 32 * K + kt);
            bv[r] = *(const uint4*)(bBase + (size_t)r * 32 * K + kt);
        }
        #pragma unroll
        for (int r = 0; r < 4; ++r) {
            *(uint4*)(asDst + r * 32 * 64) = av[r];
            *(uint4*)(bsDst + r * 32 * 64) = bv[r];
        }
        __syncthreads();
        #pragma unroll
        for (int kk = 0; kk < 64; kk += 32) {
            bf16x8 fa[4], fb[4];
            #pragma unroll
            for (int m = 0; m < 4; ++m)
                fa[m] = *(const bf16x8*)(&As[(wm * 64 + m * 16 + lr) * 64 + kk + kq * 8]);
            #pragma unroll
            for (int n = 0; n < 4; ++n)
                fb[n] = *(const bf16x8*)(&Bs[(wn * 64 + n * 16 + lr) * 64 + kk + kq * 8]);
            #pragma unroll
            for (int m = 0; m < 4; ++m)
                #pragma unroll
                for (int n = 0; n < 4; ++n)
                    acc[m][n] = __builtin_amdgcn_mfma_f32_16x16x32_bf16(fa[m], fb[n], acc[m][n], 0, 0, 0);
        }
        __syncthreads();
    }

    // epilogue: C/D layout col = lane&15, row = (lane>>4)*4 + j
    #pragma unroll
    for (int n = 0; n < 4; ++n) {
        int col = colBase + wn * 64 + n * 16 + lr;
        float bcol = bias[col];
        #pragma unroll
        for (int m = 0; m < 4; ++m) {
            #pragma unroll
            for (int j = 0; j < 4; ++j) {
                int row = rowBase + wm * 64 + m * 16 + kq * 4 + j;
                float v = acc[m][n][j] + bcol;
                if (OUT_BF16) {
                    ((unsigned short*)C)[(size_t)row * Nn + col] = f2bf(v);
                } else {
                    if (row < Mstore)
                        ((float*)C)[(size_t)row * Nn + col] = v;
                }
            }
        }
    }
}

// ---------------- GATv2 attention: one wave per destination node ----------------
__global__ void __launch_bounds__(256)
attn_kernel(const unsigned short* __restrict__ xl, const unsigned short* __restrict__ xr,
            const int* __restrict__ rowp, const int* __restrict__ colv,
            const float* __restrict__ att, const float* __restrict__ bias,
            unsigned short* __restrict__ out) {
    const int lane = threadIdx.x & 63;
    const int node = blockIdx.x * 4 + (threadIdx.x >> 6);
    const int j0 = lane * 16;     // element base in [0,1024)

    if (node >= NNODES) {
        if (node < MPAD) {
            uint4 z; z.x = z.y = z.z = z.w = 0u;
            *(uint4*)(out + (size_t)node * D2 + j0) = z;
            *(uint4*)(out + (size_t)node * D2 + j0 + 8) = z;
        }
        return;
    }

    float attv[16], xrv[16];
    #pragma unroll
    for (int q = 0; q < 4; ++q) {
        float4 t4 = *(const float4*)(att + j0 + q * 4);
        attv[4 * q] = t4.x; attv[4 * q + 1] = t4.y; attv[4 * q + 2] = t4.z; attv[4 * q + 3] = t4.w;
    }
    {
        uint4 v0 = *(const uint4*)(xr + (size_t)node * D2 + j0);
        uint4 v1 = *(const uint4*)(xr + (size_t)node * D2 + j0 + 8);
        unsigned u[8] = {v0.x, v0.y, v0.z, v0.w, v1.x, v1.y, v1.z, v1.w};
        #pragma unroll
        for (int q = 0; q < 8; ++q) unpk(u[q], xrv[2 * q], xrv[2 * q + 1]);
    }

    float acc[16];
    #pragma unroll
    for (int q = 0; q < 16; ++q) acc[q] = 0.f;
    float mrun = -1e30f, lsum = 0.f;

    const int p0 = rowp[node], p1 = rowp[node + 1];
    for (int p = p0; p < p1; ++p) {
        int s = colv[p];
        float xs[16];
        uint4 v0 = *(const uint4*)(xl + (size_t)s * D2 + j0);
        uint4 v1 = *(const uint4*)(xl + (size_t)s * D2 + j0 + 8);
        unsigned u[8] = {v0.x, v0.y, v0.z, v0.w, v1.x, v1.y, v1.z, v1.w};
        #pragma unroll
        for (int q = 0; q < 8; ++q) unpk(u[q], xs[2 * q], xs[2 * q + 1]);

        float part = 0.f;
        #pragma unroll
        for (int q = 0; q < 16; ++q) {
            float v = xs[q] + xrv[q];
            v = (v > 0.f) ? v : 0.2f * v;
            part += v * attv[q];
        }
        part += __shfl_xor(part, 1);
        part += __shfl_xor(part, 2);
        part += __shfl_xor(part, 4);
        part += __shfl_xor(part, 8);
        // online softmax update
        float mn = fmaxf(mrun, part);
        float sc = __expf(mrun - mn);
        float pw = __expf(part - mn);
        lsum = lsum * sc + pw;
        #pragma unroll
        for (int q = 0; q < 16; ++q) acc[q] = acc[q] * sc + pw * xs[q];
        mrun = mn;
    }

    float inv = 1.f / lsum;
    unsigned w[8];
    #pragma unroll
    for (int q = 0; q < 8; ++q) {
        float o0 = acc[2 * q] * inv + bias[j0 + 2 * q];
        float o1 = acc[2 * q + 1] * inv + bias[j0 + 2 * q + 1];
        o0 = (o0 > 0.f) ? o0 : (expf(o0) - 1.f);   // ELU
        o1 = (o1 > 0.f) ? o1 : (expf(o1) - 1.f);
        w[q] = (unsigned)f2bf(o0) | ((unsigned)f2bf(o1) << 16);
    }
    uint4 s0, s1;
    s0.x = w[0]; s0.y = w[1]; s0.z = w[2]; s0.w = w[3];
    s1.x = w[4]; s1.y = w[5]; s1.z = w[6]; s1.w = w[7];
    *(uint4*)(out + (size_t)node * D2 + j0) = s0;
    *(uint4*)(out + (size_t)node * D2 + j0 + 8) = s1;
}

// ---------------- host launch ----------------
extern "C" void kernel_launch(void* const* d_in, const int* in_sizes, int n_in,
                              void* d_out, int out_size, void* d_ws, size_t ws_size,
                              hipStream_t stream) {
    const float* emb   = (const float*)d_in[0];
    const float* noise = (const float*)d_in[1];
    const int*   tarr  = (const int*)d_in[2];
    const int*   ei    = (const int*)d_in[3];
    const float* Wl1   = (const float*)d_in[4];
    const float* bl1   = (const float*)d_in[5];
    const float* Wr1   = (const float*)d_in[6];
    const float* br1   = (const float*)d_in[7];
    const float* att1  = (const float*)d_in[8];
    const float* bias1 = (const float*)d_in[9];
    const float* Wl2   = (const float*)d_in[10];
    const float* bl2   = (const float*)d_in[11];
    const float* Wr2   = (const float*)d_in[12];
    const float* br2   = (const float*)d_in[13];
    const float* att2  = (const float*)d_in[14];
    const float* bias2 = (const float*)d_in[15];
    const float* Wout  = (const float*)d_in[16];
    const float* bout  = (const float*)d_in[17];
    float* out = (float*)d_out;

    char* wsp = (char*)d_ws;
    size_t off = 0;
    auto carve = [&](size_t b) -> void* {
        void* p = wsp + off;
        off = (off + b + 255) & ~(size_t)255;
        return p;
    };
    float* sched = (float*)carve(128 * 4);
    int* cnt  = (int*)carve(NNODES * 4);
    int* rowp = (int*)carve((NNODES + 1) * 4);
    int* cur  = (int*)carve(NNODES * 4);
    int* colv = (int*)carve((NEDGES + NNODES) * 4);
    unsigned short* x0b  = (unsigned short*)carve((size_t)MPAD * FIN * 2);
    unsigned short* xlb  = (unsigned short*)carve((size_t)MPAD * D2 * 2);
    unsigned short* xrb  = (unsigned short*)carve((size_t)MPAD * D2 * 2);
    unsigned short* hb   = (unsigned short*)carve((size_t)MPAD * D2 * 2);
    unsigned short* wl1t = (unsigned short*)carve((size_t)FIN * D2 * 2);
    unsigned short* wr1t = (unsigned short*)carve((size_t)FIN * D2 * 2);
    unsigned short* wl2t = (unsigned short*)carve((size_t)D2 * D2 * 2);
    unsigned short* wr2t = (unsigned short*)carve((size_t)D2 * D2 * 2);
    unsigned short* wot  = (unsigned short*)carve((size_t)D2 * FIN * 2);

    sched_init<<<1, 64, 0, stream>>>(sched);
    csr_init<<<(NNODES + 255) / 256, 256, 0, stream>>>(cnt);
    csr_count<<<(NEDGES + 255) / 256, 256, 0, stream>>>(ei, cnt);
    csr_scan<<<1, 1024, 0, stream>>>(cnt, rowp, cur);
    csr_fill<<<(NEDGES + NNODES + 255) / 256, 256, 0, stream>>>(ei, cur, colv);

    prep_w<<<(FIN * D2 + 255) / 256, 256, 0, stream>>>(Wl1, wl1t, FIN, D2);
    prep_w<<<(FIN * D2 + 255) / 256, 256, 0, stream>>>(Wr1, wr1t, FIN, D2);
    prep_w<<<(D2 * D2 + 255) / 256, 256, 0, stream>>>(Wl2, wl2t, D2, D2);
    prep_w<<<(D2 * D2 + 255) / 256, 256, 0, stream>>>(Wr2, wr2t, D2, D2);
    prep_w<<<(D2 * FIN + 255) / 256, 256, 0, stream>>>(Wout, wot, D2, FIN);

    x0_kernel<<<(MPAD * (FIN / 4)) / 256, 256, 0, stream>>>(emb, noise, tarr, sched, x0b);

    // layer 1 GEMMs: [MPAD x 768] @ [768 x 1024]
    {
        dim3 g(79, 8);
        gemm_k<true><<<g, 256, 0, stream>>>(x0b, wl1t, bl1, xlb, FIN, D2, MPAD);
        gemm_k<true><<<g, 256, 0, stream>>>(x0b, wr1t, br1, xrb, FIN, D2, MPAD);
    }
    attn_kernel<<<MPAD / 4, 256, 0, stream>>>(xlb, xrb, rowp, colv, att1, bias1, hb);

    // layer 2 GEMMs: [MPAD x 1024] @ [1024 x 1024]
    {
        dim3 g(79, 8);
        gemm_k<true><<<g, 256, 0, stream>>>(hb, wl2t, bl2, xlb, D2, D2, MPAD);
        gemm_k<true><<<g, 256, 0, stream>>>(hb, wr2t, br2, xrb, D2, D2, MPAD);
    }
    attn_kernel<<<MPAD / 4, 256, 0, stream>>>(xlb, xrb, rowp, colv, att2, bias2, hb);

    // output GEMM: [MPAD x 1024] @ [1024 x 768] -> fp32 d_out (guarded rows)
    {
        dim3 g(79, 6);
        gemm_k<false><<<g, 256, 0, stream>>>(hb, wot, bout, out, D2, FIN, NNODES);
    }
    (void)in_sizes; (void)n_in; (void)out_size; (void)ws_size;
}

// Round 2
// 403.803 us; speedup vs baseline: 1.1797x; 1.1797x over previous
//
#include <hip/hip_runtime.h>

#define NNODES 10000
#define NEDGES 160000
#define MPAD   10112      // 79 * 128
#define FIN    768
#define D2     1024
#define D2X2   2048
#define TSTEPS 50

typedef __bf16 bf16x8 __attribute__((ext_vector_type(8)));
typedef float  f32x4  __attribute__((ext_vector_type(4)));

__device__ __forceinline__ unsigned short f2bf(float f) {
    unsigned u = __builtin_bit_cast(unsigned, f);
    u += 0x7FFFu + ((u >> 16) & 1u);
    return (unsigned short)(u >> 16);
}
__device__ __forceinline__ void unpk(unsigned u, float& a, float& b) {
    a = __builtin_bit_cast(float, u << 16);
    b = __builtin_bit_cast(float, u & 0xFFFF0000u);
}
__device__ __forceinline__ void gload16(const void* g, void* l) {
    __builtin_amdgcn_global_load_lds((const __attribute__((address_space(1))) void*)g,
                                     (__attribute__((address_space(3))) void*)l, 16, 0, 0);
}

// ---------------- schedule (cosine) ----------------
__global__ void sched_init(float* sched) {
    if (threadIdx.x == 0 && blockIdx.x == 0) {
        const double PI = 3.14159265358979323846;
        double acp = 1.0;
        for (int i = 0; i < TSTEPS; ++i) {
            double x0 = (double)i / (double)TSTEPS;
            double x1 = (double)(i + 1) / (double)TSTEPS;
            double c0 = cos((x0 + 0.008) / 1.008 * PI * 0.5);
            double c1 = cos((x1 + 0.008) / 1.008 * PI * 0.5);
            double a0 = c0 * c0, a1 = c1 * c1;
            double beta = 1.0 - a1 / a0;
            if (beta < 0.0) beta = 0.0;
            if (beta > 0.999) beta = 0.999;
            acp *= (1.0 - beta);
            sched[i]      = (float)sqrt(acp);
            sched[64 + i] = (float)sqrt(1.0 - acp);
        }
    }
}

// ---------------- CSR build ----------------
__global__ void csr_init(int* cnt) {
    int g = blockIdx.x * 256 + threadIdx.x;
    if (g < NNODES) cnt[g] = 1;   // self loop
}
__global__ void csr_count(const int* __restrict__ ei, int* cnt) {
    int g = blockIdx.x * 256 + threadIdx.x;
    if (g < NEDGES) atomicAdd(&cnt[ei[NEDGES + g]], 1);
}
__global__ void csr_scan(const int* __restrict__ cnt, int* rowp, int* cur) {
    __shared__ int part[1024];
    int tid = threadIdx.x;
    const int per = 10;
    int base = tid * per;
    int local[per];
    int s = 0;
    #pragma unroll
    for (int i = 0; i < per; ++i) {
        int idx = base + i;
        int v = (idx < NNODES) ? cnt[idx] : 0;
        local[i] = s;
        s += v;
    }
    part[tid] = s;
    __syncthreads();
    for (int off = 1; off < 1024; off <<= 1) {
        int v = (tid >= off) ? part[tid - off] : 0;
        __syncthreads();
        part[tid] += v;
        __syncthreads();
    }
    int offset = (tid > 0) ? part[tid - 1] : 0;
    #pragma unroll
    for (int i = 0; i < per; ++i) {
        int idx = base + i;
        if (idx < NNODES) {
            int v = offset + local[i];
            rowp[idx] = v;
            cur[idx]  = v;
        } else if (idx == NNODES) {
            rowp[NNODES] = offset + local[i];
        }
    }
}
__global__ void csr_fill(const int* __restrict__ ei, int* cur, int* colv) {
    int g = blockIdx.x * 256 + threadIdx.x;
    if (g < NEDGES) {
        int s = ei[g];
        int d = ei[NEDGES + g];
        int pos = atomicAdd(&cur[d], 1);
        colv[pos] = s;
    } else if (g < NEDGES + NNODES) {
        int d = g - NEDGES;
        int pos = atomicAdd(&cur[d], 1);
        colv[pos] = d;
    }
}

// ---------------- weight prep: fp32 [K][Nn] -> bf16 [Nn][K] ----------------
__global__ void prep_w(const float* __restrict__ W, unsigned short* __restrict__ Wt,
                       int K, int Nn) {
    int g = blockIdx.x * 256 + threadIdx.x;
    if (g >= K * Nn) return;
    int n = g / K, k = g % K;
    Wt[g] = f2bf(W[(size_t)k * Nn + n]);
}

// ---------------- diffusion noise add -> bf16 ----------------
__global__ void x0_kernel(const float* __restrict__ emb, const float* __restrict__ noise,
                          const int* __restrict__ t, const float* __restrict__ sched,
                          unsigned short* __restrict__ x0b) {
    int i4 = blockIdx.x * 256 + threadIdx.x;
    if (i4 >= MPAD * (FIN / 4)) return;
    int row = i4 / (FIN / 4);
    int c = (i4 % (FIN / 4)) * 4;
    unsigned short* dst = x0b + (size_t)row * FIN + c;
    if (row < NNODES) {
        int tv = t[row];
        float sa = sched[tv], so = sched[64 + tv];
        float4 e = *(const float4*)(emb + (size_t)row * FIN + c);
        float4 nz = *(const float4*)(noise + (size_t)row * FIN + c);
        float v0 = sa * e.x + so * nz.x;
        float v1 = sa * e.y + so * nz.y;
        float v2 = sa * e.z + so * nz.z;
        float v3 = sa * e.w + so * nz.w;
        uint2 pk;
        pk.x = (unsigned)f2bf(v0) | ((unsigned)f2bf(v1) << 16);
        pk.y = (unsigned)f2bf(v2) | ((unsigned)f2bf(v3) << 16);
        *(uint2*)dst = pk;
    } else {
        uint2 pk; pk.x = 0u; pk.y = 0u;
        *(uint2*)dst = pk;
    }
}

// ---------------- bf16 MFMA GEMM (global_load_lds staging) ----------------
// C[M][Nn] = A[M][K] @ Bt[Nn][K]^T + bias
template<bool OUT_BF16>
__global__ void __launch_bounds__(256)
gemm_k(const unsigned short* __restrict__ A, const unsigned short* __restrict__ Bt,
       const float* __restrict__ bias, void* __restrict__ C,
       int K, int Nn, int Mstore) {
    __shared__ __align__(16) unsigned short As[128 * 64];
    __shared__ __align__(16) unsigned short Bs[128 * 64];

    const int tid = threadIdx.x;
    const int lane = tid & 63;
    const int wv = tid >> 6;
    const int wm = wv >> 1, wn = wv & 1;
    const int lr = lane & 15;
    const int kq = lane >> 4;

    const int rowBase = blockIdx.x * 128;
    const int colBase = blockIdx.y * 128;

    f32x4 acc[4][4];
    #pragma unroll
    for (int m = 0; m < 4; ++m)
        #pragma unroll
        for (int n = 0; n < 4; ++n)
            acc[m][n] = (f32x4){0.f, 0.f, 0.f, 0.f};

    // staging geometry: per wave, 4 instrs for A + 4 for B; instr i covers
    // 8 rows starting at r0 = i*32 + wv*8; lane l -> row r0 + (l>>3), elems (l&7)*8
    const int lrow = lane >> 3;
    const int lcol = (lane & 7) * 8;

    for (int kt = 0; kt < K; kt += 64) {
        #pragma unroll
        for (int i = 0; i < 4; ++i) {
            const int r0 = i * 32 + wv * 8;
            const unsigned short* ga = A  + (size_t)(rowBase + r0 + lrow) * K + kt + lcol;
            const unsigned short* gb = Bt + (size_t)(colBase + r0 + lrow) * K + kt + lcol;
            gload16(ga, &As[r0 * 64]);
            gload16(gb, &Bs[r0 * 64]);
        }
        __syncthreads();
        #pragma unroll
        for (int kk = 0; kk < 64; kk += 32) {
            bf16x8 fa[4], fb[4];
            #pragma unroll
            for (int m = 0; m < 4; ++m)
                fa[m] = *(const bf16x8*)(&As[(wm * 64 + m * 16 + lr) * 64 + kk + kq * 8]);
            #pragma unroll
            for (int n = 0; n < 4; ++n)
                fb[n] = *(const bf16x8*)(&Bs[(wn * 64 + n * 16 + lr) * 64 + kk + kq * 8]);
            #pragma unroll
            for (int m = 0; m < 4; ++m)
                #pragma unroll
                for (int n = 0; n < 4; ++n)
                    acc[m][n] = __builtin_amdgcn_mfma_f32_16x16x32_bf16(fa[m], fb[n], acc[m][n], 0, 0, 0);
        }
        __syncthreads();
    }

    // epilogue: C/D layout col = lane&15, row = (lane>>4)*4 + j
    #pragma unroll
    for (int n = 0; n < 4; ++n) {
        int col = colBase + wn * 64 + n * 16 + lr;
        float bcol = bias[col];
        #pragma unroll
        for (int m = 0; m < 4; ++m) {
            #pragma unroll
            for (int j = 0; j < 4; ++j) {
                int row = rowBase + wm * 64 + m * 16 + kq * 4 + j;
                float v = acc[m][n][j] + bcol;
                if (OUT_BF16) {
                    ((unsigned short*)C)[(size_t)row * Nn + col] = f2bf(v);
                } else {
                    if (row < Mstore)
                        ((float*)C)[(size_t)row * Nn + col] = v;
                }
            }
        }
    }
}

// ---------------- GATv2 attention: one wave per destination node ----------------
// xlr: [MPAD][2048] bf16, xl = cols [0,1024), xr = cols [1024,2048)
__global__ void __launch_bounds__(256)
attn_kernel(const unsigned short* __restrict__ xlr,
            const int* __restrict__ rowp, const int* __restrict__ colv,
            const float* __restrict__ att, const float* __restrict__ bias,
            unsigned short* __restrict__ out) {
    const int lane = threadIdx.x & 63;
    const int node = blockIdx.x * 4 + (threadIdx.x >> 6);
    const int j0 = lane * 16;     // element base in [0,1024)

    if (node >= NNODES) {
        if (node < MPAD) {
            uint4 z; z.x = z.y = z.z = z.w = 0u;
            *(uint4*)(out + (size_t)node * D2 + j0) = z;
            *(uint4*)(out + (size_t)node * D2 + j0 + 8) = z;
        }
        return;
    }

    float attv[16], xrv[16];
    #pragma unroll
    for (int q = 0; q < 4; ++q) {
        float4 t4 = *(const float4*)(att + j0 + q * 4);
        attv[4 * q] = t4.x; attv[4 * q + 1] = t4.y; attv[4 * q + 2] = t4.z; attv[4 * q + 3] = t4.w;
    }
    {
        const unsigned short* xr = xlr + (size_t)node * D2X2 + D2 + j0;
        uint4 v0 = *(const uint4*)(xr);
        uint4 v1 = *(const uint4*)(xr + 8);
        unsigned u[8] = {v0.x, v0.y, v0.z, v0.w, v1.x, v1.y, v1.z, v1.w};
        #pragma unroll
        for (int q = 0; q < 8; ++q) unpk(u[q], xrv[2 * q], xrv[2 * q + 1]);
    }

    float acc[16];
    #pragma unroll
    for (int q = 0; q < 16; ++q) acc[q] = 0.f;
    float mbase = 8.0f;       // fixed softmax base; logits here are O(1) << 8
    float lsum = 0.f;

    const int p0 = rowp[node], p1 = rowp[node + 1];

    // 1-deep software prefetch of the gathered xl row
    int s0i = colv[p0];
    uint4 c0 = *(const uint4*)(xlr + (size_t)s0i * D2X2 + j0);
    uint4 c1 = *(const uint4*)(xlr + (size_t)s0i * D2X2 + j0 + 8);

    for (int p = p0; p < p1; ++p) {
        int pn = (p + 1 < p1) ? p + 1 : p;
        int sn = colv[pn];
        uint4 n0 = *(const uint4*)(xlr + (size_t)sn * D2X2 + j0);
        uint4 n1 = *(const uint4*)(xlr + (size_t)sn * D2X2 + j0 + 8);

        float xs[16];
        {
            unsigned u[8] = {c0.x, c0.y, c0.z, c0.w, c1.x, c1.y, c1.z, c1.w};
            #pragma unroll
            for (int q = 0; q < 8; ++q) unpk(u[q], xs[2 * q], xs[2 * q + 1]);
        }

        float part = 0.f;
        #pragma unroll
        for (int q = 0; q < 16; ++q) {
            float v = xs[q] + xrv[q];
            v = fmaxf(v, 0.2f * v);      // leaky_relu (slope 0.2 < 1)
            part += v * attv[q];
        }
        part += __shfl_xor(part, 1);
        part += __shfl_xor(part, 2);
        part += __shfl_xor(part, 4);
        part += __shfl_xor(part, 8);

        if (__builtin_expect(part > mbase, 0)) {
            float sc = __expf(mbase - part);
            lsum *= sc;
            #pragma unroll
            for (int q = 0; q < 16; ++q) acc[q] *= sc;
            mbase = part;
        }
        float pw = __expf(part - mbase);
        lsum += pw;
        #pragma unroll
        for (int q = 0; q < 16; ++q) acc[q] += pw * xs[q];

        c0 = n0; c1 = n1;
    }

    float inv = 1.f / lsum;
    unsigned w[8];
    #pragma unroll
    for (int q = 0; q < 8; ++q) {
        float o0 = acc[2 * q] * inv + bias[j0 + 2 * q];
        float o1 = acc[2 * q + 1] * inv + bias[j0 + 2 * q + 1];
        o0 = (o0 > 0.f) ? o0 : (__expf(o0) - 1.f);   // ELU
        o1 = (o1 > 0.f) ? o1 : (__expf(o1) - 1.f);
        w[q] = (unsigned)f2bf(o0) | ((unsigned)f2bf(o1) << 16);
    }
    uint4 v0, v1;
    v0.x = w[0]; v0.y = w[1]; v0.z = w[2]; v0.w = w[3];
    v1.x = w[4]; v1.y = w[5]; v1.z = w[6]; v1.w = w[7];
    *(uint4*)(out + (size_t)node * D2 + j0) = v0;
    *(uint4*)(out + (size_t)node * D2 + j0 + 8) = v1;
}

// ---------------- host launch ----------------
extern "C" void kernel_launch(void* const* d_in, const int* in_sizes, int n_in,
                              void* d_out, int out_size, void* d_ws, size_t ws_size,
                              hipStream_t stream) {
    const float* emb   = (const float*)d_in[0];
    const float* noise = (const float*)d_in[1];
    const int*   tarr  = (const int*)d_in[2];
    const int*   ei    = (const int*)d_in[3];
    const float* Wl1   = (const float*)d_in[4];
    const float* bl1   = (const float*)d_in[5];
    const float* Wr1   = (const float*)d_in[6];
    const float* br1   = (const float*)d_in[7];
    const float* att1  = (const float*)d_in[8];
    const float* bias1 = (const float*)d_in[9];
    const float* Wl2   = (const float*)d_in[10];
    const float* bl2   = (const float*)d_in[11];
    const float* Wr2   = (const float*)d_in[12];
    const float* br2   = (const float*)d_in[13];
    const float* att2  = (const float*)d_in[14];
    const float* bias2 = (const float*)d_in[15];
    const float* Wout  = (const float*)d_in[16];
    const float* bout  = (const float*)d_in[17];
    float* out = (float*)d_out;

    char* wsp = (char*)d_ws;
    size_t off = 0;
    auto carve = [&](size_t b) -> void* {
        void* p = wsp + off;
        off = (off + b + 255) & ~(size_t)255;
        return p;
    };
    float* sched = (float*)carve(128 * 4);
    int* cnt  = (int*)carve(NNODES * 4);
    int* rowp = (int*)carve((NNODES + 1) * 4);
    int* cur  = (int*)carve(NNODES * 4);
    int* colv = (int*)carve((NEDGES + NNODES) * 4);
    float* biasC1 = (float*)carve(D2X2 * 4);
    float* biasC2 = (float*)carve(D2X2 * 4);
    unsigned short* x0b   = (unsigned short*)carve((size_t)MPAD * FIN * 2);
    unsigned short* xlrb  = (unsigned short*)carve((size_t)MPAD * D2X2 * 2);
    unsigned short* hb    = (unsigned short*)carve((size_t)MPAD * D2 * 2);
    unsigned short* wlr1t = (unsigned short*)carve((size_t)FIN * D2X2 * 2);
    unsigned short* wlr2t = (unsigned short*)carve((size_t)D2 * D2X2 * 2);
    unsigned short* wot   = (unsigned short*)carve((size_t)D2 * FIN * 2);

    sched_init<<<1, 64, 0, stream>>>(sched);
    csr_init<<<(NNODES + 255) / 256, 256, 0, stream>>>(cnt);
    csr_count<<<(NEDGES + 255) / 256, 256, 0, stream>>>(ei, cnt);
    csr_scan<<<1, 1024, 0, stream>>>(cnt, rowp, cur);
    csr_fill<<<(NEDGES + NNODES + 255) / 256, 256, 0, stream>>>(ei, cur, colv);

    // combined biases via d2d async copies
    hipMemcpyAsync(biasC1,      bl1, D2 * 4, hipMemcpyDeviceToDevice, stream);
    hipMemcpyAsync(biasC1 + D2, br1, D2 * 4, hipMemcpyDeviceToDevice, stream);
    hipMemcpyAsync(biasC2,      bl2, D2 * 4, hipMemcpyDeviceToDevice, stream);
    hipMemcpyAsync(biasC2 + D2, br2, D2 * 4, hipMemcpyDeviceToDevice, stream);

    // combined transposed weights: rows [0,1024) = Wl, rows [1024,2048) = Wr
    prep_w<<<(FIN * D2 + 255) / 256, 256, 0, stream>>>(Wl1, wlr1t, FIN, D2);
    prep_w<<<(FIN * D2 + 255) / 256, 256, 0, stream>>>(Wr1, wlr1t + (size_t)D2 * FIN, FIN, D2);
    prep_w<<<(D2 * D2 + 255) / 256, 256, 0, stream>>>(Wl2, wlr2t, D2, D2);
    prep_w<<<(D2 * D2 + 255) / 256, 256, 0, stream>>>(Wr2, wlr2t + (size_t)D2 * D2, D2, D2);
    prep_w<<<(D2 * FIN + 255) / 256, 256, 0, stream>>>(Wout, wot, D2, FIN);

    x0_kernel<<<(MPAD * (FIN / 4)) / 256, 256, 0, stream>>>(emb, noise, tarr, sched, x0b);

    // layer 1 fused GEMM: [MPAD x 768] @ [768 x 2048] -> xlrb
    {
        dim3 g(79, 16);
        gemm_k<true><<<g, 256, 0, stream>>>(x0b, wlr1t, biasC1, xlrb, FIN, D2X2, MPAD);
    }
    attn_kernel<<<MPAD / 4, 256, 0, stream>>>(xlrb, rowp, colv, att1, bias1, hb);

    // layer 2 fused GEMM: [MPAD x 1024] @ [1024 x 2048] -> xlrb
    {
        dim3 g(79, 16);
        gemm_k<true><<<g, 256, 0, stream>>>(hb, wlr2t, biasC2, xlrb, D2, D2X2, MPAD);
    }
    attn_kernel<<<MPAD / 4, 256, 0, stream>>>(xlrb, rowp, colv, att2, bias2, hb);

    // output GEMM: [MPAD x 1024] @ [1024 x 768] -> fp32 d_out (guarded rows)
    {
        dim3 g(79, 6);
        gemm_k<false><<<g, 256, 0, stream>>>(hb, wot, bout, out, D2, FIN, NNODES);
    }
    (void)in_sizes; (void)n_in; (void)out_size; (void)ws_size;
}

// Round 3
// 353.875 us; speedup vs baseline: 1.3461x; 1.1411x over previous
//
#include <hip/hip_runtime.h>

#define NNODES 10000
#define NEDGES 160000
#define MPAD   10240      // 40 * 256
#define FIN    768
#define D2     1024
#define D2X2   2048
#define TSTEPS 50

#define RING_STRIDE 49152          // A 32KB + B 16KB per ring slot
#define LDS_BYTES   147456         // 3 ring slots

typedef __bf16 bf16x8 __attribute__((ext_vector_type(8)));
typedef float  f32x4  __attribute__((ext_vector_type(4)));

__device__ __forceinline__ unsigned short f2bf(float f) {
    unsigned u = __builtin_bit_cast(unsigned, f);
    u += 0x7FFFu + ((u >> 16) & 1u);
    return (unsigned short)(u >> 16);
}
__device__ __forceinline__ void unpk(unsigned u, float& a, float& b) {
    a = __builtin_bit_cast(float, u << 16);
    b = __builtin_bit_cast(float, u & 0xFFFF0000u);
}
__device__ __forceinline__ void gload16(const void* g, void* l) {
    __builtin_amdgcn_global_load_lds((const __attribute__((address_space(1))) void*)g,
                                     (__attribute__((address_space(3))) void*)l, 16, 0, 0);
}

// ---------------- schedule (cosine) ----------------
__global__ void sched_init(float* sched) {
    if (threadIdx.x == 0 && blockIdx.x == 0) {
        const double PI = 3.14159265358979323846;
        double acp = 1.0;
        for (int i = 0; i < TSTEPS; ++i) {
            double x0 = (double)i / (double)TSTEPS;
            double x1 = (double)(i + 1) / (double)TSTEPS;
            double c0 = cos((x0 + 0.008) / 1.008 * PI * 0.5);
            double c1 = cos((x1 + 0.008) / 1.008 * PI * 0.5);
            double a0 = c0 * c0, a1 = c1 * c1;
            double beta = 1.0 - a1 / a0;
            if (beta < 0.0) beta = 0.0;
            if (beta > 0.999) beta = 0.999;
            acp *= (1.0 - beta);
            sched[i]      = (float)sqrt(acp);
            sched[64 + i] = (float)sqrt(1.0 - acp);
        }
    }
}

// ---------------- CSR build ----------------
__global__ void csr_init(int* cnt) {
    int g = blockIdx.x * 256 + threadIdx.x;
    if (g < NNODES) cnt[g] = 1;   // self loop
}
__global__ void csr_count(const int* __restrict__ ei, int* cnt) {
    int g = blockIdx.x * 256 + threadIdx.x;
    if (g < NEDGES) atomicAdd(&cnt[ei[NEDGES + g]], 1);
}
__global__ void csr_scan(const int* __restrict__ cnt, int* rowp, int* cur) {
    __shared__ int part[1024];
    int tid = threadIdx.x;
    const int per = 10;
    int base = tid * per;
    int local[per];
    int s = 0;
    #pragma unroll
    for (int i = 0; i < per; ++i) {
        int idx = base + i;
        int v = (idx < NNODES) ? cnt[idx] : 0;
        local[i] = s;
        s += v;
    }
    part[tid] = s;
    __syncthreads();
    for (int off = 1; off < 1024; off <<= 1) {
        int v = (tid >= off) ? part[tid - off] : 0;
        __syncthreads();
        part[tid] += v;
        __syncthreads();
    }
    int offset = (tid > 0) ? part[tid - 1] : 0;
    #pragma unroll
    for (int i = 0; i < per; ++i) {
        int idx = base + i;
        if (idx < NNODES) {
            int v = offset + local[i];
            rowp[idx] = v;
            cur[idx]  = v;
        } else if (idx == NNODES) {
            rowp[NNODES] = offset + local[i];
        }
    }
}
__global__ void csr_fill(const int* __restrict__ ei, int* cur, int* colv) {
    int g = blockIdx.x * 256 + threadIdx.x;
    if (g < NEDGES) {
        int s = ei[g];
        int d = ei[NEDGES + g];
        int pos = atomicAdd(&cur[d], 1);
        colv[pos] = s;
    } else if (g < NEDGES + NNODES) {
        int d = g - NEDGES;
        int pos = atomicAdd(&cur[d], 1);
        colv[pos] = d;
    }
}

// ---------------- weight transpose: fp32 [K][Nn] -> bf16 [Nn][K], LDS-tiled ----------------
__global__ void prep_w_t(const float* __restrict__ W, unsigned short* __restrict__ Wt,
                         int K, int Nn) {
    __shared__ float tile[32][33];
    const int kb = blockIdx.x * 32, nb = blockIdx.y * 32;
    const int tx = threadIdx.x & 31, ty = threadIdx.x >> 5;   // 256 thr: ty 0..7
    #pragma unroll
    for (int i = 0; i < 32; i += 8)
        tile[ty + i][tx] = W[(size_t)(kb + ty + i) * Nn + nb + tx];   // coalesced read
    __syncthreads();
    #pragma unroll
    for (int i = 0; i < 32; i += 8)
        Wt[(size_t)(nb + ty + i) * K + kb + tx] = f2bf(tile[tx][ty + i]);  // coalesced write
}

// ---------------- diffusion noise add -> bf16 ----------------
__global__ void x0_kernel(const float* __restrict__ emb, const float* __restrict__ noise,
                          const int* __restrict__ t, const float* __restrict__ sched,
                          unsigned short* __restrict__ x0b) {
    int i4 = blockIdx.x * 256 + threadIdx.x;
    if (i4 >= MPAD * (FIN / 4)) return;
    int row = i4 / (FIN / 4);
    int c = (i4 % (FIN / 4)) * 4;
    unsigned short* dst = x0b + (size_t)row * FIN + c;
    if (row < NNODES) {
        int tv = t[row];
        float sa = sched[tv], so = sched[64 + tv];
        float4 e = *(const float4*)(emb + (size_t)row * FIN + c);
        float4 nz = *(const float4*)(noise + (size_t)row * FIN + c);
        float v0 = sa * e.x + so * nz.x;
        float v1 = sa * e.y + so * nz.y;
        float v2 = sa * e.z + so * nz.z;
        float v3 = sa * e.w + so * nz.w;
        uint2 pk;
        pk.x = (unsigned)f2bf(v0) | ((unsigned)f2bf(v1) << 16);
        pk.y = (unsigned)f2bf(v2) | ((unsigned)f2bf(v3) << 16);
        *(uint2*)dst = pk;
    } else {
        uint2 pk; pk.x = 0u; pk.y = 0u;
        *(uint2*)dst = pk;
    }
}

// ---------------- pipelined bf16 MFMA GEMM ----------------
// C[M][Nn] = A[M][K] @ Bt[Nn][K]^T + bias
// BM=256, BN=128, BK=64, 512 threads (8 waves, 4M x 2N, wave tile 64x64)
// 3-deep LDS ring, counted vmcnt, T2 xor-swizzle, T5 setprio, T1 xcd swizzle.

// stage one K-tile (A 256x64 + B 128x64) into ring slot; 6 gload16 per thread
__device__ __forceinline__ void stage_ab(const unsigned short* __restrict__ A,
                                         const unsigned short* __restrict__ Bt,
                                         char* ldsbase, int rowBase, int colBase,
                                         int kt, int K, int tid) {
    const int r8 = tid >> 3;             // 0..63
    const int cb = (tid & 7) * 16;       // byte col within 128B row
    const size_t Kb = (size_t)K * 2;
    #pragma unroll
    for (int i = 0; i < 4; ++i) {        // A: 4 rounds x 64 rows
        int r = i * 64 + r8;
        int scb = cb ^ ((r & 7) << 4);   // inverse-swizzled source
        gload16((const char*)A + (size_t)(rowBase + r) * Kb + (size_t)kt * 2 + scb,
                ldsbase + r * 128 + cb);
    }
    #pragma unroll
    for (int i = 0; i < 2; ++i) {        // B: 2 rounds x 64 rows
        int r = i * 64 + r8;
        int scb = cb ^ ((r & 7) << 4);
        gload16((const char*)Bt + (size_t)(colBase + r) * Kb + (size_t)kt * 2 + scb,
                ldsbase + 32768 + r * 128 + cb);
    }
}

template<bool OUT_BF16>
__global__ void __launch_bounds__(512, 1)
gemm8(const unsigned short* __restrict__ A, const unsigned short* __restrict__ Bt,
      const float* __restrict__ bias, void* __restrict__ C,
      int K, int Nn, int Mstore, int gy) {
    extern __shared__ char lds[];
    const int tid = threadIdx.x;
    const int lane = tid & 63;
    const int wv = tid >> 6;          // 0..7
    const int wm = wv >> 1;           // 0..3 : 64-row block of 256
    const int wn = wv & 1;            // 0..1 : 64-col block of 128
    const int lr = lane & 15;
    const int kq = lane >> 4;

    // T1: bijective XCD swizzle (m204), by-fastest within chunk
    const int total = gridDim.x;
    {
    }
    int lin = blockIdx.x;
    int q = total >> 3, r = total & 7;
    int xcd = lin & 7, idx = lin >> 3;
    int lin2 = (xcd < r ? xcd * (q + 1) : r * (q + 1) + (xcd - r) * q) + idx;
    const int rowBase = (lin2 / gy) * 256;
    const int colBase = (lin2 % gy) * 128;

    f32x4 acc[4][4];
    #pragma unroll
    for (int m = 0; m < 4; ++m)
        #pragma unroll
        for (int n = 0; n < 4; ++n)
            acc[m][n] = (f32x4){0.f, 0.f, 0.f, 0.f};

    const int NT = K >> 6;
    stage_ab(A, Bt, lds,               rowBase, colBase, 0,  K, tid);
    stage_ab(A, Bt, lds + RING_STRIDE, rowBase, colBase, 64, K, tid);

    for (int t = 0; t < NT; ++t) {
        // wave's own tile-t loads landed (oldest 6 of <=12 outstanding)
        if (t < NT - 1) asm volatile("s_waitcnt vmcnt(6)" ::: "memory");
        else            asm volatile("s_waitcnt vmcnt(0)" ::: "memory");
        __builtin_amdgcn_s_barrier();           // all waves' tile-t data resident
        asm volatile("" ::: "memory");
        if (t + 2 < NT)
            stage_ab(A, Bt, lds + ((t + 2) % 3) * RING_STRIDE, rowBase, colBase,
                     (t + 2) * 64, K, tid);
        const char* la = lds + (t % 3) * RING_STRIDE;
        const char* lb = la + 32768;
        #pragma unroll
        for (int k2 = 0; k2 < 2; ++k2) {
            bf16x8 fa[4], fb[4];
            #pragma unroll
            for (int m = 0; m < 4; ++m) {
                int fr = wm * 64 + m * 16 + lr;
                int off = (fr * 128 + k2 * 64 + kq * 16) ^ ((fr & 7) << 4);  // T2 swizzled read
                fa[m] = *(const bf16x8*)(la + off);
            }
            #pragma unroll
            for (int n = 0; n < 4; ++n) {
                int fr = wn * 64 + n * 16 + lr;
                int off = (fr * 128 + k2 * 64 + kq * 16) ^ ((fr & 7) << 4);
                fb[n] = *(const bf16x8*)(lb + off);
            }
            __builtin_amdgcn_s_setprio(1);
            #pragma unroll
            for (int m = 0; m < 4; ++m)
                #pragma unroll
                for (int n = 0; n < 4; ++n)
                    acc[m][n] = __builtin_amdgcn_mfma_f32_16x16x32_bf16(fa[m], fb[n], acc[m][n], 0, 0, 0);
            __builtin_amdgcn_s_setprio(0);
        }
    }

    // epilogue: col = lane&15, row = kq*4 + j
    #pragma unroll
    for (int n = 0; n < 4; ++n) {
        int col = colBase + wn * 64 + n * 16 + lr;
        float bcol = bias[col];
        #pragma unroll
        for (int m = 0; m < 4; ++m) {
            int row0 = rowBase + wm * 64 + m * 16 + kq * 4;
            #pragma unroll
            for (int j = 0; j < 4; ++j) {
                float v = acc[m][n][j] + bcol;
                if (OUT_BF16) {
                    ((unsigned short*)C)[(size_t)(row0 + j) * Nn + col] = f2bf(v);
                } else {
                    if (row0 + j < Mstore)
                        ((float*)C)[(size_t)(row0 + j) * Nn + col] = v;
                }
            }
        }
    }
}

// ---------------- GATv2 attention: one wave per destination node ----------------
// xlr: [MPAD][2048] bf16, xl = cols [0,1024), xr = cols [1024,2048)
__global__ void __launch_bounds__(256)
attn_kernel(const unsigned short* __restrict__ xlr,
            const int* __restrict__ rowp, const int* __restrict__ colv,
            const float* __restrict__ att, const float* __restrict__ bias,
            unsigned short* __restrict__ out) {
    const int lane = threadIdx.x & 63;
    const int node = blockIdx.x * 4 + (threadIdx.x >> 6);
    const int j0 = lane * 16;     // element base in [0,1024)

    if (node >= NNODES) {
        if (node < MPAD) {
            uint4 z; z.x = z.y = z.z = z.w = 0u;
            *(uint4*)(out + (size_t)node * D2 + j0) = z;
            *(uint4*)(out + (size_t)node * D2 + j0 + 8) = z;
        }
        return;
    }

    float attv[16], xrv[16];
    #pragma unroll
    for (int q = 0; q < 4; ++q) {
        float4 t4 = *(const float4*)(att + j0 + q * 4);
        attv[4 * q] = t4.x; attv[4 * q + 1] = t4.y; attv[4 * q + 2] = t4.z; attv[4 * q + 3] = t4.w;
    }
    {
        const unsigned short* xr = xlr + (size_t)node * D2X2 + D2 + j0;
        uint4 v0 = *(const uint4*)(xr);
        uint4 v1 = *(const uint4*)(xr + 8);
        unsigned u[8] = {v0.x, v0.y, v0.z, v0.w, v1.x, v1.y, v1.z, v1.w};
        #pragma unroll
        for (int q = 0; q < 8; ++q) unpk(u[q], xrv[2 * q], xrv[2 * q + 1]);
    }

    float acc[16];
    #pragma unroll
    for (int q = 0; q < 16; ++q) acc[q] = 0.f;
    float mbase = 8.0f;       // fixed softmax base; logits here are O(1) << 8
    float lsum = 0.f;

    const int p0 = rowp[node], p1 = rowp[node + 1];

    // 2-deep software prefetch of the gathered xl rows
    int sA = colv[p0];
    int sB = (p0 + 1 < p1) ? colv[p0 + 1] : sA;
    uint4 a0 = *(const uint4*)(xlr + (size_t)sA * D2X2 + j0);
    uint4 a1 = *(const uint4*)(xlr + (size_t)sA * D2X2 + j0 + 8);
    uint4 b0 = *(const uint4*)(xlr + (size_t)sB * D2X2 + j0);
    uint4 b1 = *(const uint4*)(xlr + (size_t)sB * D2X2 + j0 + 8);

    for (int p = p0; p < p1; ++p) {
        int sN = (p + 2 < p1) ? colv[p + 2] : sA;
        uint4 f0 = *(const uint4*)(xlr + (size_t)sN * D2X2 + j0);
        uint4 f1 = *(const uint4*)(xlr + (size_t)sN * D2X2 + j0 + 8);

        float xs[16];
        {
            unsigned u[8] = {a0.x, a0.y, a0.z, a0.w, a1.x, a1.y, a1.z, a1.w};
            #pragma unroll
            for (int q = 0; q < 8; ++q) unpk(u[q], xs[2 * q], xs[2 * q + 1]);
        }

        float part = 0.f;
        #pragma unroll
        for (int q = 0; q < 16; ++q) {
            float v = xs[q] + xrv[q];
            v = fmaxf(v, 0.2f * v);      // leaky_relu (slope 0.2 < 1)
            part += v * attv[q];
        }
        part += __shfl_xor(part, 1);
        part += __shfl_xor(part, 2);
        part += __shfl_xor(part, 4);
        part += __shfl_xor(part, 8);

        if (__builtin_expect(part > mbase, 0)) {
            float sc = __expf(mbase - part);
            lsum *= sc;
            #pragma unroll
            for (int q = 0; q < 16; ++q) acc[q] *= sc;
            mbase = part;
        }
        float pw = __expf(part - mbase);
        lsum += pw;
        #pragma unroll
        for (int q = 0; q < 16; ++q) acc[q] += pw * xs[q];

        a0 = b0; a1 = b1; b0 = f0; b1 = f1;
    }

    float inv = 1.f / lsum;
    unsigned w[8];
    #pragma unroll
    for (int q = 0; q < 8; ++q) {
        float o0 = acc[2 * q] * inv + bias[j0 + 2 * q];
        float o1 = acc[2 * q + 1] * inv + bias[j0 + 2 * q + 1];
        o0 = (o0 > 0.f) ? o0 : (__expf(o0) - 1.f);   // ELU
        o1 = (o1 > 0.f) ? o1 : (__expf(o1) - 1.f);
        w[q] = (unsigned)f2bf(o0) | ((unsigned)f2bf(o1) << 16);
    }
    uint4 v0, v1;
    v0.x = w[0]; v0.y = w[1]; v0.z = w[2]; v0.w = w[3];
    v1.x = w[4]; v1.y = w[5]; v1.z = w[6]; v1.w = w[7];
    *(uint4*)(out + (size_t)node * D2 + j0) = v0;
    *(uint4*)(out + (size_t)node * D2 + j0 + 8) = v1;
}

// ---------------- host launch ----------------
extern "C" void kernel_launch(void* const* d_in, const int* in_sizes, int n_in,
                              void* d_out, int out_size, void* d_ws, size_t ws_size,
                              hipStream_t stream) {
    const float* emb   = (const float*)d_in[0];
    const float* noise = (const float*)d_in[1];
    const int*   tarr  = (const int*)d_in[2];
    const int*   ei    = (const int*)d_in[3];
    const float* Wl1   = (const float*)d_in[4];
    const float* bl1   = (const float*)d_in[5];
    const float* Wr1   = (const float*)d_in[6];
    const float* br1   = (const float*)d_in[7];
    const float* att1  = (const float*)d_in[8];
    const float* bias1 = (const float*)d_in[9];
    const float* Wl2   = (const float*)d_in[10];
    const float* bl2   = (const float*)d_in[11];
    const float* Wr2   = (const float*)d_in[12];
    const float* br2   = (const float*)d_in[13];
    const float* att2  = (const float*)d_in[14];
    const float* bias2 = (const float*)d_in[15];
    const float* Wout  = (const float*)d_in[16];
    const float* bout  = (const float*)d_in[17];
    float* out = (float*)d_out;

    char* wsp = (char*)d_ws;
    size_t off = 0;
    auto carve = [&](size_t b) -> void* {
        void* p = wsp + off;
        off = (off + b + 255) & ~(size_t)255;
        return p;
    };
    float* sched = (float*)carve(128 * 4);
    int* cnt  = (int*)carve(NNODES * 4);
    int* rowp = (int*)carve((NNODES + 1) * 4);
    int* cur  = (int*)carve(NNODES * 4);
    int* colv = (int*)carve((NEDGES + NNODES) * 4);
    float* biasC1 = (float*)carve(D2X2 * 4);
    float* biasC2 = (float*)carve(D2X2 * 4);
    unsigned short* x0b   = (unsigned short*)carve((size_t)MPAD * FIN * 2);
    unsigned short* xlrb  = (unsigned short*)carve((size_t)MPAD * D2X2 * 2);
    unsigned short* hb    = (unsigned short*)carve((size_t)MPAD * D2 * 2);
    unsigned short* wlr1t = (unsigned short*)carve((size_t)FIN * D2X2 * 2);
    unsigned short* wlr2t = (unsigned short*)carve((size_t)D2 * D2X2 * 2);
    unsigned short* wot   = (unsigned short*)carve((size_t)D2 * FIN * 2);

    // allow 144KB dynamic LDS on the gemm kernels (idempotent, host-side)
    {
        auto* f1 = gemm8<true>;
        auto* f2 = gemm8<false>;
        hipFuncSetAttribute(reinterpret_cast<const void*>(f1),
                            hipFuncAttributeMaxDynamicSharedMemorySize, LDS_BYTES);
        hipFuncSetAttribute(reinterpret_cast<const void*>(f2),
                            hipFuncAttributeMaxDynamicSharedMemorySize, LDS_BYTES);
    }

    sched_init<<<1, 64, 0, stream>>>(sched);
    csr_init<<<(NNODES + 255) / 256, 256, 0, stream>>>(cnt);
    csr_count<<<(NEDGES + 255) / 256, 256, 0, stream>>>(ei, cnt);
    csr_scan<<<1, 1024, 0, stream>>>(cnt, rowp, cur);
    csr_fill<<<(NEDGES + NNODES + 255) / 256, 256, 0, stream>>>(ei, cur, colv);

    // combined biases via d2d async copies
    hipMemcpyAsync(biasC1,      bl1, D2 * 4, hipMemcpyDeviceToDevice, stream);
    hipMemcpyAsync(biasC1 + D2, br1, D2 * 4, hipMemcpyDeviceToDevice, stream);
    hipMemcpyAsync(biasC2,      bl2, D2 * 4, hipMemcpyDeviceToDevice, stream);
    hipMemcpyAsync(biasC2 + D2, br2, D2 * 4, hipMemcpyDeviceToDevice, stream);

    // combined transposed weights: rows [0,1024) = Wl, rows [1024,2048) = Wr
    {
        dim3 b(256);
        prep_w_t<<<dim3(FIN / 32, D2 / 32), b, 0, stream>>>(Wl1, wlr1t, FIN, D2);
        prep_w_t<<<dim3(FIN / 32, D2 / 32), b, 0, stream>>>(Wr1, wlr1t + (size_t)D2 * FIN, FIN, D2);
        prep_w_t<<<dim3(D2 / 32, D2 / 32),  b, 0, stream>>>(Wl2, wlr2t, D2, D2);
        prep_w_t<<<dim3(D2 / 32, D2 / 32),  b, 0, stream>>>(Wr2, wlr2t + (size_t)D2 * D2, D2, D2);
        prep_w_t<<<dim3(D2 / 32, FIN / 32), b, 0, stream>>>(Wout, wot, D2, FIN);
    }

    x0_kernel<<<(MPAD * (FIN / 4)) / 256, 256, 0, stream>>>(emb, noise, tarr, sched, x0b);

    // layer 1 fused GEMM: [MPAD x 768] @ [768 x 2048] -> xlrb
    gemm8<true><<<dim3((MPAD / 256) * (D2X2 / 128)), 512, LDS_BYTES, stream>>>(
        x0b, wlr1t, biasC1, xlrb, FIN, D2X2, MPAD, D2X2 / 128);
    attn_kernel<<<MPAD / 4, 256, 0, stream>>>(xlrb, rowp, colv, att1, bias1, hb);

    // layer 2 fused GEMM: [MPAD x 1024] @ [1024 x 2048] -> xlrb
    gemm8<true><<<dim3((MPAD / 256) * (D2X2 / 128)), 512, LDS_BYTES, stream>>>(
        hb, wlr2t, biasC2, xlrb, D2, D2X2, MPAD, D2X2 / 128);
    attn_kernel<<<MPAD / 4, 256, 0, stream>>>(xlrb, rowp, colv, att2, bias2, hb);

    // output GEMM: [MPAD x 1024] @ [1024 x 768] -> fp32 d_out (guarded rows)
    gemm8<false><<<dim3((MPAD / 256) * (FIN / 128)), 512, LDS_BYTES, stream>>>(
        hb, wot, bout, out, D2, FIN, NNODES, FIN / 128);

    (void)in_sizes; (void)n_in; (void)out_size; (void)ws_size;
}

// Round 4
// 352.956 us; speedup vs baseline: 1.3496x; 1.0026x over previous
//
#include <hip/hip_runtime.h>

#define NNODES 10000
#define NEDGES 160000
#define MPAD   10240      // 40 * 256
#define FIN    768
#define D2     1024
#define D2X2   2048
#define TSTEPS 50

#define RING_STRIDE 49152          // A 32KB + B 16KB per ring slot
#define LDS_BYTES   147456         // 3 ring slots

typedef __bf16 bf16x8 __attribute__((ext_vector_type(8)));
typedef float  f32x4  __attribute__((ext_vector_type(4)));

__device__ __forceinline__ unsigned short f2bf(float f) {
    unsigned u = __builtin_bit_cast(unsigned, f);
    u += 0x7FFFu + ((u >> 16) & 1u);
    return (unsigned short)(u >> 16);
}
__device__ __forceinline__ void unpk(unsigned u, float& a, float& b) {
    a = __builtin_bit_cast(float, u << 16);
    b = __builtin_bit_cast(float, u & 0xFFFF0000u);
}
__device__ __forceinline__ void gload16(const void* g, void* l) {
    __builtin_amdgcn_global_load_lds((const __attribute__((address_space(1))) void*)g,
                                     (__attribute__((address_space(3))) void*)l, 16, 0, 0);
}

// ---------------- schedule (cosine) ----------------
__global__ void sched_init(float* sched) {
    if (threadIdx.x == 0 && blockIdx.x == 0) {
        const double PI = 3.14159265358979323846;
        double acp = 1.0;
        for (int i = 0; i < TSTEPS; ++i) {
            double x0 = (double)i / (double)TSTEPS;
            double x1 = (double)(i + 1) / (double)TSTEPS;
            double c0 = cos((x0 + 0.008) / 1.008 * PI * 0.5);
            double c1 = cos((x1 + 0.008) / 1.008 * PI * 0.5);
            double a0 = c0 * c0, a1 = c1 * c1;
            double beta = 1.0 - a1 / a0;
            if (beta < 0.0) beta = 0.0;
            if (beta > 0.999) beta = 0.999;
            acp *= (1.0 - beta);
            sched[i]      = (float)sqrt(acp);
            sched[64 + i] = (float)sqrt(1.0 - acp);
        }
    }
}

// ---------------- CSR build ----------------
__global__ void csr_init(int* cnt) {
    int g = blockIdx.x * 256 + threadIdx.x;
    if (g < NNODES) cnt[g] = 1;   // self loop
}
__global__ void csr_count(const int* __restrict__ ei, int* cnt) {
    int g = blockIdx.x * 256 + threadIdx.x;
    if (g < NEDGES) atomicAdd(&cnt[ei[NEDGES + g]], 1);
}
__global__ void csr_scan(const int* __restrict__ cnt, int* rowp, int* cur) {
    __shared__ int part[1024];
    int tid = threadIdx.x;
    const int per = 10;
    int base = tid * per;
    int local[per];
    int s = 0;
    #pragma unroll
    for (int i = 0; i < per; ++i) {
        int idx = base + i;
        int v = (idx < NNODES) ? cnt[idx] : 0;
        local[i] = s;
        s += v;
    }
    part[tid] = s;
    __syncthreads();
    for (int off = 1; off < 1024; off <<= 1) {
        int v = (tid >= off) ? part[tid - off] : 0;
        __syncthreads();
        part[tid] += v;
        __syncthreads();
    }
    int offset = (tid > 0) ? part[tid - 1] : 0;
    #pragma unroll
    for (int i = 0; i < per; ++i) {
        int idx = base + i;
        if (idx < NNODES) {
            int v = offset + local[i];
            rowp[idx] = v;
            cur[idx]  = v;
        } else if (idx == NNODES) {
            rowp[NNODES] = offset + local[i];
        }
    }
}
__global__ void csr_fill(const int* __restrict__ ei, int* cur, int* colv) {
    int g = blockIdx.x * 256 + threadIdx.x;
    if (g < NEDGES) {
        int s = ei[g];
        int d = ei[NEDGES + g];
        int pos = atomicAdd(&cur[d], 1);
        colv[pos] = s;
    } else if (g < NEDGES + NNODES) {
        int d = g - NEDGES;
        int pos = atomicAdd(&cur[d], 1);
        colv[pos] = d;
    }
}

// ---------------- weight transpose: fp32 [K][Nn] -> bf16 [Nn][K], LDS-tiled ----------------
__global__ void prep_w_t(const float* __restrict__ W, unsigned short* __restrict__ Wt,
                         int K, int Nn) {
    __shared__ float tile[32][33];
    const int kb = blockIdx.x * 32, nb = blockIdx.y * 32;
    const int tx = threadIdx.x & 31, ty = threadIdx.x >> 5;   // 256 thr: ty 0..7
    #pragma unroll
    for (int i = 0; i < 32; i += 8)
        tile[ty + i][tx] = W[(size_t)(kb + ty + i) * Nn + nb + tx];   // coalesced read
    __syncthreads();
    #pragma unroll
    for (int i = 0; i < 32; i += 8)
        Wt[(size_t)(nb + ty + i) * K + kb + tx] = f2bf(tile[tx][ty + i]);  // coalesced write
}

// ---------------- diffusion noise add -> bf16 ----------------
__global__ void x0_kernel(const float* __restrict__ emb, const float* __restrict__ noise,
                          const int* __restrict__ t, const float* __restrict__ sched,
                          unsigned short* __restrict__ x0b) {
    int i4 = blockIdx.x * 256 + threadIdx.x;
    if (i4 >= MPAD * (FIN / 4)) return;
    int row = i4 / (FIN / 4);
    int c = (i4 % (FIN / 4)) * 4;
    unsigned short* dst = x0b + (size_t)row * FIN + c;
    if (row < NNODES) {
        int tv = t[row];
        float sa = sched[tv], so = sched[64 + tv];
        float4 e = *(const float4*)(emb + (size_t)row * FIN + c);
        float4 nz = *(const float4*)(noise + (size_t)row * FIN + c);
        float v0 = sa * e.x + so * nz.x;
        float v1 = sa * e.y + so * nz.y;
        float v2 = sa * e.z + so * nz.z;
        float v3 = sa * e.w + so * nz.w;
        uint2 pk;
        pk.x = (unsigned)f2bf(v0) | ((unsigned)f2bf(v1) << 16);
        pk.y = (unsigned)f2bf(v2) | ((unsigned)f2bf(v3) << 16);
        *(uint2*)dst = pk;
    } else {
        uint2 pk; pk.x = 0u; pk.y = 0u;
        *(uint2*)dst = pk;
    }
}

// ---------------- pipelined bf16 MFMA GEMM, 2-phase-per-K-tile ----------------
// C[M][Nn] = A[M][K] @ Bt[Nn][K]^T + bias
// BM=256, BN=128, BK=64, 512 threads (8 waves, 4M x 2N, wave tile 64x64)
// 3-deep LDS ring, counted vmcnt, T2 xor-swizzle, T3 phase split, T5 setprio, T1 xcd swizzle.

__device__ __forceinline__ void stage_a4(const unsigned short* __restrict__ A,
                                         char* ldsbase, int rowBase, int kt, int K, int tid) {
    const int r8 = tid >> 3;             // 0..63
    const int cb = (tid & 7) * 16;       // byte col within 128B row
    const size_t Kb = (size_t)K * 2;
    #pragma unroll
    for (int i = 0; i < 4; ++i) {        // A: 4 rounds x 64 rows
        int r = i * 64 + r8;
        int scb = cb ^ ((r & 7) << 4);   // inverse-swizzled source
        gload16((const char*)A + (size_t)(rowBase + r) * Kb + (size_t)kt * 2 + scb,
                ldsbase + r * 128 + cb);
    }
}
__device__ __forceinline__ void stage_b2(const unsigned short* __restrict__ Bt,
                                         char* ldsbase, int colBase, int kt, int K, int tid) {
    const int r8 = tid >> 3;
    const int cb = (tid & 7) * 16;
    const size_t Kb = (size_t)K * 2;
    #pragma unroll
    for (int i = 0; i < 2; ++i) {        // B: 2 rounds x 64 rows
        int r = i * 64 + r8;
        int scb = cb ^ ((r & 7) << 4);
        gload16((const char*)Bt + (size_t)(colBase + r) * Kb + (size_t)kt * 2 + scb,
                ldsbase + 32768 + r * 128 + cb);
    }
}

template<bool OUT_BF16>
__global__ void __launch_bounds__(512, 1)
gemm8(const unsigned short* __restrict__ A, const unsigned short* __restrict__ Bt,
      const float* __restrict__ bias, void* __restrict__ C,
      int K, int Nn, int Mstore, int gy) {
    extern __shared__ char lds[];
    const int tid = threadIdx.x;
    const int lane = tid & 63;
    const int wv = tid >> 6;          // 0..7
    const int wm = wv >> 1;           // 0..3 : 64-row block of 256
    const int wn = wv & 1;            // 0..1 : 64-col block of 128
    const int lr = lane & 15;
    const int kq = lane >> 4;

    // T1: bijective XCD swizzle (m204)
    const int total = gridDim.x;
    int lin = blockIdx.x;
    int q = total >> 3, r = total & 7;
    int xcd = lin & 7, idx = lin >> 3;
    int lin2 = (xcd < r ? xcd * (q + 1) : r * (q + 1) + (xcd - r) * q) + idx;
    const int rowBase = (lin2 / gy) * 256;
    const int colBase = (lin2 % gy) * 128;

    f32x4 acc[4][4];
    #pragma unroll
    for (int m = 0; m < 4; ++m)
        #pragma unroll
        for (int n = 0; n < 4; ++n)
            acc[m][n] = (f32x4){0.f, 0.f, 0.f, 0.f};

    const int NT = K >> 6;
    stage_a4(A, lds, rowBase, 0, K, tid);
    stage_b2(Bt, lds, colBase, 0, K, tid);
    stage_a4(A, lds + RING_STRIDE, rowBase, 64, K, tid);
    stage_b2(Bt, lds + RING_STRIDE, colBase, 64, K, tid);

    for (int t = 0; t < NT; ++t) {
        // gate: tile-t data resident in all waves' view
        if (t < NT - 1) asm volatile("s_waitcnt vmcnt(6)" ::: "memory");
        else            asm volatile("s_waitcnt vmcnt(0)" ::: "memory");
        __builtin_amdgcn_s_barrier();
        asm volatile("" ::: "memory");

        const char* la = lds + (t % 3) * RING_STRIDE;
        const char* lb = la + 32768;
        const bool pf = (t + 2 < NT);
        char* pdst = lds + ((t + 2) % 3) * RING_STRIDE;
        const int pkt = (t + 2) * 64;

        bf16x8 fa[4], fb[4];
        // ---------- phase 0: k-slice 0 ----------
        #pragma unroll
        for (int m = 0; m < 4; ++m) {
            int fr = wm * 64 + m * 16 + lr;
            fa[m] = *(const bf16x8*)(la + ((fr * 128 + kq * 16) ^ ((fr & 7) << 4)));
        }
        #pragma unroll
        for (int n = 0; n < 4; ++n) {
            int fr = wn * 64 + n * 16 + lr;
            fb[n] = *(const bf16x8*)(lb + ((fr * 128 + kq * 16) ^ ((fr & 7) << 4)));
        }
        if (pf) stage_a4(A, pdst, rowBase, pkt, K, tid);
        __builtin_amdgcn_sched_barrier(0);
        __builtin_amdgcn_s_barrier();
        asm volatile("" ::: "memory");
        __builtin_amdgcn_s_setprio(1);
        #pragma unroll
        for (int m = 0; m < 4; ++m)
            #pragma unroll
            for (int n = 0; n < 4; ++n)
                acc[m][n] = __builtin_amdgcn_mfma_f32_16x16x32_bf16(fa[m], fb[n], acc[m][n], 0, 0, 0);
        __builtin_amdgcn_s_setprio(0);
        __builtin_amdgcn_sched_barrier(0);

        // ---------- phase 1: k-slice 1 ----------
        #pragma unroll
        for (int m = 0; m < 4; ++m) {
            int fr = wm * 64 + m * 16 + lr;
            fa[m] = *(const bf16x8*)(la + ((fr * 128 + 64 + kq * 16) ^ ((fr & 7) << 4)));
        }
        #pragma unroll
        for (int n = 0; n < 4; ++n) {
            int fr = wn * 64 + n * 16 + lr;
            fb[n] = *(const bf16x8*)(lb + ((fr * 128 + 64 + kq * 16) ^ ((fr & 7) << 4)));
        }
        if (pf) stage_b2(Bt, pdst, colBase, pkt, K, tid);
        __builtin_amdgcn_sched_barrier(0);
        __builtin_amdgcn_s_barrier();
        asm volatile("" ::: "memory");
        __builtin_amdgcn_s_setprio(1);
        #pragma unroll
        for (int m = 0; m < 4; ++m)
            #pragma unroll
            for (int n = 0; n < 4; ++n)
                acc[m][n] = __builtin_amdgcn_mfma_f32_16x16x32_bf16(fa[m], fb[n], acc[m][n], 0, 0, 0);
        __builtin_amdgcn_s_setprio(0);
        __builtin_amdgcn_sched_barrier(0);
    }

    // epilogue: col = lane&15, row = kq*4 + j
    #pragma unroll
    for (int n = 0; n < 4; ++n) {
        int col = colBase + wn * 64 + n * 16 + lr;
        float bcol = bias[col];
        #pragma unroll
        for (int m = 0; m < 4; ++m) {
            int row0 = rowBase + wm * 64 + m * 16 + kq * 4;
            #pragma unroll
            for (int j = 0; j < 4; ++j) {
                float v = acc[m][n][j] + bcol;
                if (OUT_BF16) {
                    ((unsigned short*)C)[(size_t)(row0 + j) * Nn + col] = f2bf(v);
                } else {
                    if (row0 + j < Mstore)
                        ((float*)C)[(size_t)(row0 + j) * Nn + col] = v;
                }
            }
        }
    }
}

// ---------------- GATv2 attention: one wave per destination node ----------------
// xlr: [MPAD][2048] bf16, xl = cols [0,1024), xr = cols [1024,2048)
__global__ void __launch_bounds__(256)
attn_kernel(const unsigned short* __restrict__ xlr,
            const int* __restrict__ rowp, const int* __restrict__ colv,
            const float* __restrict__ att, const float* __restrict__ bias,
            unsigned short* __restrict__ out) {
    const int lane = threadIdx.x & 63;
    const int node = blockIdx.x * 4 + (threadIdx.x >> 6);
    const int j0 = lane * 16;     // element base in [0,1024)

    if (node >= NNODES) {
        if (node < MPAD) {
            uint4 z; z.x = z.y = z.z = z.w = 0u;
            *(uint4*)(out + (size_t)node * D2 + j0) = z;
            *(uint4*)(out + (size_t)node * D2 + j0 + 8) = z;
        }
        return;
    }

    float attv[16], xrv[16];
    #pragma unroll
    for (int q = 0; q < 4; ++q) {
        float4 t4 = *(const float4*)(att + j0 + q * 4);
        attv[4 * q] = t4.x; attv[4 * q + 1] = t4.y; attv[4 * q + 2] = t4.z; attv[4 * q + 3] = t4.w;
    }
    {
        const unsigned short* xr = xlr + (size_t)node * D2X2 + D2 + j0;
        uint4 v0 = *(const uint4*)(xr);
        uint4 v1 = *(const uint4*)(xr + 8);
        unsigned u[8] = {v0.x, v0.y, v0.z, v0.w, v1.x, v1.y, v1.z, v1.w};
        #pragma unroll
        for (int q = 0; q < 8; ++q) unpk(u[q], xrv[2 * q], xrv[2 * q + 1]);
    }

    float acc[16];
    #pragma unroll
    for (int q = 0; q < 16; ++q) acc[q] = 0.f;
    float mbase = 8.0f;       // fixed softmax base; logits here are O(1) << 8
    float lsum = 0.f;

    const int p0 = rowp[node], p1 = rowp[node + 1];

    // 2-deep software prefetch of the gathered xl rows
    int sA = colv[p0];
    int sB = (p0 + 1 < p1) ? colv[p0 + 1] : sA;
    uint4 a0 = *(const uint4*)(xlr + (size_t)sA * D2X2 + j0);
    uint4 a1 = *(const uint4*)(xlr + (size_t)sA * D2X2 + j0 + 8);
    uint4 b0 = *(const uint4*)(xlr + (size_t)sB * D2X2 + j0);
    uint4 b1 = *(const uint4*)(xlr + (size_t)sB * D2X2 + j0 + 8);

    for (int p = p0; p < p1; ++p) {
        int sN = (p + 2 < p1) ? colv[p + 2] : sA;
        uint4 f0 = *(const uint4*)(xlr + (size_t)sN * D2X2 + j0);
        uint4 f1 = *(const uint4*)(xlr + (size_t)sN * D2X2 + j0 + 8);

        float xs[16];
        {
            unsigned u[8] = {a0.x, a0.y, a0.z, a0.w, a1.x, a1.y, a1.z, a1.w};
            #pragma unroll
            for (int q = 0; q < 8; ++q) unpk(u[q], xs[2 * q], xs[2 * q + 1]);
        }

        float part = 0.f;
        #pragma unroll
        for (int q = 0; q < 16; ++q) {
            float v = xs[q] + xrv[q];
            v = fmaxf(v, 0.2f * v);      // leaky_relu (slope 0.2 < 1)
            part += v * attv[q];
        }
        part += __shfl_xor(part, 1);
        part += __shfl_xor(part, 2);
        part += __shfl_xor(part, 4);
        part += __shfl_xor(part, 8);

        if (__builtin_expect(part > mbase, 0)) {
            float sc = __expf(mbase - part);
            lsum *= sc;
            #pragma unroll
            for (int q = 0; q < 16; ++q) acc[q] *= sc;
            mbase = part;
        }
        float pw = __expf(part - mbase);
        lsum += pw;
        #pragma unroll
        for (int q = 0; q < 16; ++q) acc[q] += pw * xs[q];

        a0 = b0; a1 = b1; b0 = f0; b1 = f1;
    }

    float inv = 1.f / lsum;
    unsigned w[8];
    #pragma unroll
    for (int q = 0; q < 8; ++q) {
        float o0 = acc[2 * q] * inv + bias[j0 + 2 * q];
        float o1 = acc[2 * q + 1] * inv + bias[j0 + 2 * q + 1];
        o0 = (o0 > 0.f) ? o0 : (__expf(o0) - 1.f);   // ELU
        o1 = (o1 > 0.f) ? o1 : (__expf(o1) - 1.f);
        w[q] = (unsigned)f2bf(o0) | ((unsigned)f2bf(o1) << 16);
    }
    uint4 v0, v1;
    v0.x = w[0]; v0.y = w[1]; v0.z = w[2]; v0.w = w[3];
    v1.x = w[4]; v1.y = w[5]; v1.z = w[6]; v1.w = w[7];
    *(uint4*)(out + (size_t)node * D2 + j0) = v0;
    *(uint4*)(out + (size_t)node * D2 + j0 + 8) = v1;
}

// ---------------- host launch ----------------
extern "C" void kernel_launch(void* const* d_in, const int* in_sizes, int n_in,
                              void* d_out, int out_size, void* d_ws, size_t ws_size,
                              hipStream_t stream) {
    const float* emb   = (const float*)d_in[0];
    const float* noise = (const float*)d_in[1];
    const int*   tarr  = (const int*)d_in[2];
    const int*   ei    = (const int*)d_in[3];
    const float* Wl1   = (const float*)d_in[4];
    const float* bl1   = (const float*)d_in[5];
    const float* Wr1   = (const float*)d_in[6];
    const float* br1   = (const float*)d_in[7];
    const float* att1  = (const float*)d_in[8];
    const float* bias1 = (const float*)d_in[9];
    const float* Wl2   = (const float*)d_in[10];
    const float* bl2   = (const float*)d_in[11];
    const float* Wr2   = (const float*)d_in[12];
    const float* br2   = (const float*)d_in[13];
    const float* att2  = (const float*)d_in[14];
    const float* bias2 = (const float*)d_in[15];
    const float* Wout  = (const float*)d_in[16];
    const float* bout  = (const float*)d_in[17];
    float* out = (float*)d_out;

    char* wsp = (char*)d_ws;
    size_t off = 0;
    auto carve = [&](size_t b) -> void* {
        void* p = wsp + off;
        off = (off + b + 255) & ~(size_t)255;
        return p;
    };
    float* sched = (float*)carve(128 * 4);
    int* cnt  = (int*)carve(NNODES * 4);
    int* rowp = (int*)carve((NNODES + 1) * 4);
    int* cur  = (int*)carve(NNODES * 4);
    int* colv = (int*)carve((NEDGES + NNODES) * 4);
    float* biasC1 = (float*)carve(D2X2 * 4);
    float* biasC2 = (float*)carve(D2X2 * 4);
    unsigned short* x0b   = (unsigned short*)carve((size_t)MPAD * FIN * 2);
    unsigned short* xlrb  = (unsigned short*)carve((size_t)MPAD * D2X2 * 2);
    unsigned short* hb    = (unsigned short*)carve((size_t)MPAD * D2 * 2);
    unsigned short* wlr1t = (unsigned short*)carve((size_t)FIN * D2X2 * 2);
    unsigned short* wlr2t = (unsigned short*)carve((size_t)D2 * D2X2 * 2);
    unsigned short* wot   = (unsigned short*)carve((size_t)D2 * FIN * 2);

    // allow 144KB dynamic LDS on the gemm kernels (idempotent, host-side)
    {
        auto* f1 = gemm8<true>;
        auto* f2 = gemm8<false>;
        hipFuncSetAttribute(reinterpret_cast<const void*>(f1),
                            hipFuncAttributeMaxDynamicSharedMemorySize, LDS_BYTES);
        hipFuncSetAttribute(reinterpret_cast<const void*>(f2),
                            hipFuncAttributeMaxDynamicSharedMemorySize, LDS_BYTES);
    }

    sched_init<<<1, 64, 0, stream>>>(sched);
    csr_init<<<(NNODES + 255) / 256, 256, 0, stream>>>(cnt);
    csr_count<<<(NEDGES + 255) / 256, 256, 0, stream>>>(ei, cnt);
    csr_scan<<<1, 1024, 0, stream>>>(cnt, rowp, cur);
    csr_fill<<<(NEDGES + NNODES + 255) / 256, 256, 0, stream>>>(ei, cur, colv);

    // combined biases via d2d async copies
    hipMemcpyAsync(biasC1,      bl1, D2 * 4, hipMemcpyDeviceToDevice, stream);
    hipMemcpyAsync(biasC1 + D2, br1, D2 * 4, hipMemcpyDeviceToDevice, stream);
    hipMemcpyAsync(biasC2,      bl2, D2 * 4, hipMemcpyDeviceToDevice, stream);
    hipMemcpyAsync(biasC2 + D2, br2, D2 * 4, hipMemcpyDeviceToDevice, stream);

    // combined transposed weights: rows [0,1024) = Wl, rows [1024,2048) = Wr
    {
        dim3 b(256);
        prep_w_t<<<dim3(FIN / 32, D2 / 32), b, 0, stream>>>(Wl1, wlr1t, FIN, D2);
        prep_w_t<<<dim3(FIN / 32, D2 / 32), b, 0, stream>>>(Wr1, wlr1t + (size_t)D2 * FIN, FIN, D2);
        prep_w_t<<<dim3(D2 / 32, D2 / 32),  b, 0, stream>>>(Wl2, wlr2t, D2, D2);
        prep_w_t<<<dim3(D2 / 32, D2 / 32),  b, 0, stream>>>(Wr2, wlr2t + (size_t)D2 * D2, D2, D2);
        prep_w_t<<<dim3(D2 / 32, FIN / 32), b, 0, stream>>>(Wout, wot, D2, FIN);
    }

    x0_kernel<<<(MPAD * (FIN / 4)) / 256, 256, 0, stream>>>(emb, noise, tarr, sched, x0b);

    // layer 1 fused GEMM: [MPAD x 768] @ [768 x 2048] -> xlrb
    gemm8<true><<<dim3((MPAD / 256) * (D2X2 / 128)), 512, LDS_BYTES, stream>>>(
        x0b, wlr1t, biasC1, xlrb, FIN, D2X2, MPAD, D2X2 / 128);
    attn_kernel<<<MPAD / 4, 256, 0, stream>>>(xlrb, rowp, colv, att1, bias1, hb);

    // layer 2 fused GEMM: [MPAD x 1024] @ [1024 x 2048] -> xlrb
    gemm8<true><<<dim3((MPAD / 256) * (D2X2 / 128)), 512, LDS_BYTES, stream>>>(
        hb, wlr2t, biasC2, xlrb, D2, D2X2, MPAD, D2X2 / 128);
    attn_kernel<<<MPAD / 4, 256, 0, stream>>>(xlrb, rowp, colv, att2, bias2, hb);

    // output GEMM: [MPAD x 1024] @ [1024 x 768] -> fp32 d_out (guarded rows)
    gemm8<false><<<dim3((MPAD / 256) * (FIN / 128)), 512, LDS_BYTES, stream>>>(
        hb, wot, bout, out, D2, FIN, NNODES, FIN / 128);

    (void)in_sizes; (void)n_in; (void)out_size; (void)ws_size;
}